// Round 4
// baseline (153.879 us; speedup 1.0000x reference)
//
#include <hip/hip_runtime.h>
#include <cstdint>
#include <cstddef>

#define NB 512
#define NL 32
#define KD 512    // P*D
#define HKD 256   // k-half per pass

// swizzled float-offset of chunk ch (4 floats) of row `row` in a [32][256] pass buffer.
__device__ __forceinline__ int swz_off(int row, int ch) {
  int csw = (ch & ~15) | ((ch ^ (row >> 1)) & 15);
  return row * HKD + csw * 4;
}

// ---------------- cost kernel: 512 blocks x 256 thr ----------------
__global__ __launch_bounds__(256, 2)
void cost_kernel(const float* __restrict__ pred, const float* __restrict__ tgt,
                 float* __restrict__ cost_g) {
  __shared__ float smem[16384];   // 64 KB staging; later 4x1024 partials
  const int b = blockIdx.x;
  const int tid = threadIdx.x;
  float* predH = smem;
  float* tgtH  = smem + 8192;

  const int w = tid >> 6, l = tid & 63;
  const int ti = l >> 3, tj = l & 7;   // 8x8 lanes of 4x4 tiles, wave w owns a k-slice
  float acc[4][4];
#pragma unroll
  for (int a = 0; a < 4; ++a)
#pragma unroll
    for (int c2 = 0; c2 < 4; ++c2) acc[a][c2] = 0.f;

  for (int hp = 0; hp < 2; ++hp) {
    __syncthreads();
    const size_t base = (size_t)b * (NL * KD) + (size_t)hp * HKD;
#pragma unroll
    for (int it = 0; it < 8; ++it) {
      int chunk = tid + it * 256;
      int row = chunk >> 6, ch = chunk & 63;
      const float4 pv = *reinterpret_cast<const float4*>(pred + base + (size_t)row * KD + ch * 4);
      const float4 tv = *reinterpret_cast<const float4*>(tgt  + base + (size_t)row * KD + ch * 4);
      int off = swz_off(row, ch);
      *reinterpret_cast<float4*>(predH + off) = pv;
      *reinterpret_cast<float4*>(tgtH  + off) = tv;
    }
    __syncthreads();
#pragma unroll
    for (int c0 = 0; c0 < 16; ++c0) {
      const int c = (w << 4) + c0;
      float4 pr[4], tg[4];
#pragma unroll
      for (int r = 0; r < 4; ++r) {
        pr[r] = *reinterpret_cast<const float4*>(predH + swz_off(4 * ti + r, c));
        tg[r] = *reinterpret_cast<const float4*>(tgtH  + swz_off(4 * tj + r, c));
      }
#pragma unroll
      for (int a = 0; a < 4; ++a)
#pragma unroll
        for (int c2 = 0; c2 < 4; ++c2) {
          float d;
          d = pr[a].x - tg[c2].x; acc[a][c2] += d * d;
          d = pr[a].y - tg[c2].y; acc[a][c2] += d * d;
          d = pr[a].z - tg[c2].z; acc[a][c2] += d * d;
          d = pr[a].w - tg[c2].w; acc[a][c2] += d * d;
        }
    }
  }
  __syncthreads();   // staging reads done; reuse LDS for partials
  // disjoint bit-field layout: bank = (ti&3)+4*tj -> 2-way max (free)
#pragma unroll
  for (int a = 0; a < 4; ++a)
#pragma unroll
    for (int c2 = 0; c2 < 4; ++c2)
      smem[w * 1024 + (ti & 3) + 4 * tj + 32 * a + 128 * c2 + 512 * (ti >> 2)] = acc[a][c2];
  __syncthreads();
  // thread t reduces outputs o = 4t..4t+3 (row = t>>3, col = 4*(t&7)+k)
  const int ti2 = tid >> 5, a2 = (tid >> 3) & 3, tj2 = tid & 7;
  float ov[4];
#pragma unroll
  for (int k = 0; k < 4; ++k) {
    int ad = (ti2 & 3) + 4 * tj2 + 32 * a2 + 128 * k + 512 * (ti2 >> 2);
    ov[k] = (smem[ad] + smem[ad + 1024]) + (smem[ad + 2048] + smem[ad + 3072]);
  }
  float4 o4 = make_float4(ov[0], ov[1], ov[2], ov[3]);
  *reinterpret_cast<float4*>(cost_g + (size_t)b * 1024 + tid * 4) = o4;
}

// ---------------- hungarian kernel: 512 blocks x 64 thr ----------------
__device__ __forceinline__ float readlane_f(float x, int lane) {
  return __int_as_float(__builtin_amdgcn_readlane(__float_as_int(x), lane));
}
__device__ __forceinline__ int readlane_i(int x, int lane) {
  return __builtin_amdgcn_readlane(x, lane);
}

template<int CTRL, int RM>
__device__ __forceinline__ float dppmin(float x) {
  int m = __builtin_amdgcn_update_dpp(__float_as_int(x), __float_as_int(x), CTRL, RM, 0xf, false);
  return fminf(x, __int_as_float(m));
}
// min over lanes 0..31, broadcast to all lanes via SGPR
__device__ __forceinline__ float wave_min32_bcast(float x) {
  x = dppmin<0xB1, 0xf>(x);   // quad_perm xor1
  x = dppmin<0x4E, 0xf>(x);   // quad_perm xor2
  x = dppmin<0x124, 0xf>(x);  // row_ror:4
  x = dppmin<0x128, 0xf>(x);  // row_ror:8 -> row16 min everywhere
  x = dppmin<0x142, 0xa>(x);  // row_bcast:15 -> lanes 16..31 = min(lanes 0..31)
  return readlane_f(x, 31);
}

// 32-to-1 register select, 31 v_cndmask (idx may be uniform or per-lane)
__device__ __forceinline__ float sel32(const float c[32], int idx) {
  float t[16];
#pragma unroll
  for (int k = 0; k < 16; ++k) t[k] = (idx & 16) ? c[k + 16] : c[k];
  float s[8];
#pragma unroll
  for (int k = 0; k < 8; ++k) s[k] = (idx & 8) ? t[k + 8] : t[k];
  float q[4];
#pragma unroll
  for (int k = 0; k < 4; ++k) q[k] = (idx & 4) ? s[k + 4] : s[k];
  float d0 = (idx & 2) ? q[2] : q[0];
  float d1 = (idx & 2) ? q[3] : q[1];
  return (idx & 1) ? d1 : d0;
}

__global__ __launch_bounds__(64)
void hung_kernel(const float* __restrict__ cost_g,
                 const float* __restrict__ prob,
                 const float* __restrict__ lmask,
                 const int* __restrict__ clf,
                 float* __restrict__ part) {
  const int b = blockIdx.x;
  const int lane = threadIdx.x;

  float lm = (lane < 32) ? lmask[b * 32 + lane] : 0.f;
  const int n = __popcll(__ballot(lm > 0.5f));
  float clfpart = 0.f;
  if (lane < 32 && lm > 0.5f) {
    int cc = clf[b * 32 + lane];
    clfpart = -logf(prob[(size_t)(b * 32 + lane) * 2 + cc]);
  }

  // lane j owns column j: cost[:, j] in 32 registers
  const int cl = (lane < 32) ? lane : 0;
  float c[32];
#pragma unroll
  for (int i = 0; i < 32; ++i) c[i] = cost_g[(size_t)b * 1024 + i * 32 + cl];

  const float FINF = 1e30f;
  const bool activecol = (lane < n);

  // Reference-faithful broken JV (minv/way never persisted in the python):
  // each step: fresh argmin over free cols of cost[i0][j]-u[i0]-v[j];
  // "augment" collapses to p[j_final] = ri. The uniform u[i0] doesn't affect
  // the argmin, so the min runs on key = c - v; delta = min(key) - u[i0].
  float u_r = 0.f, v_j = 0.f;
  int p_j = -1;

  for (int ri = 0; ri < n; ++ri) {
    int i0 = ri;
    bool usedc = false;
    bool usedr = (lane == ri);
    while (true) {
      float key = sel32(c, i0) - v_j;           // reduced cost (sans uniform u0)
      bool act = activecol && !usedc;
      float m = act ? key : FINF;
      float u0 = readlane_f(u_r, i0);           // off the min critical path
      float mn = wave_min32_bcast(m);
      uint64_t tie = __ballot(m == mn);
      int j1 = __ffsll((unsigned long long)tie) - 1;  // numpy first-index tie-break
      float delta = mn - u0;
      if (usedr) u_r += delta;                  // u[p[used]] += delta
      if (usedc) v_j -= delta;                  // v[used]    -= delta
      int pj1 = readlane_i(p_j, j1);
      if (pj1 < 0) {                            // free column -> p[j1] = ri, done
        if (lane == j1) p_j = ri;
        break;
      }
      usedc = usedc || (lane == j1);
      i0 = pj1;
      usedr = usedr || (lane == i0);
    }
  }

  // column j matched to row p[j] -> contributes cost[p[j]][j]
  int pj = p_j < 0 ? 0 : p_j;
  float a = activecol ? sel32(c, pj) : 0.f;
#pragma unroll
  for (int off = 32; off; off >>= 1) {
    a += __shfl_xor(a, off);
    clfpart += __shfl_xor(clfpart, off);
  }
  if (lane == 0) {
    part[b * 3 + 0] = a;
    part[b * 3 + 1] = clfpart;
    part[b * 3 + 2] = (float)n;
  }
}

// ---------------- finalize ----------------
__global__ void finalize_kernel(const float* __restrict__ part, float* __restrict__ out) {
  const int lane = threadIdx.x;   // 64 threads, 1 block: deterministic fixed-order reduce
  double cs = 0.0, ls = 0.0, ns = 0.0;
  for (int i = lane; i < NB; i += 64) {
    cs += (double)part[i * 3 + 0];
    ls += (double)part[i * 3 + 1];
    ns += (double)part[i * 3 + 2];
  }
#pragma unroll
  for (int off = 32; off; off >>= 1) {
    cs += __shfl_xor(cs, off);
    ls += __shfl_xor(ls, off);
    ns += __shfl_xor(ns, off);
  }
  if (lane == 0) {
    out[0] = (float)(cs / (ns * 256.0));  // / sum(point_masks) = 256 * sum(n)
    out[1] = (float)(ls / ns);            // / sum(line_masks)
  }
}

extern "C" void kernel_launch(void* const* d_in, const int* in_sizes, int n_in,
                              void* d_out, int out_size, void* d_ws, size_t ws_size,
                              hipStream_t stream) {
  const float* pred = (const float*)d_in[0];   // [512,32,256,2] f32
  const float* prob = (const float*)d_in[1];   // [512,32,2] f32
  const float* tgt  = (const float*)d_in[2];   // [512,32,256,2] f32
  const float* lm   = (const float*)d_in[3];   // [512,32] f32
  const int*   clf  = (const int*)d_in[4];     // [512,32] i32

  float* cost_g = (float*)d_ws;                // 512*1024 f32 = 2 MB
  float* part   = cost_g + (size_t)NB * 1024;  // 512*3 f32

  cost_kernel<<<NB, 256, 0, stream>>>(pred, tgt, cost_g);
  hung_kernel<<<NB, 64, 0, stream>>>(cost_g, prob, lm, clf, part);
  finalize_kernel<<<1, 64, 0, stream>>>(part, (float*)d_out);
}

// Round 5
// 89.600 us; speedup vs baseline: 1.7174x; 1.7174x over previous
//
#include <hip/hip_runtime.h>
#include <cstdint>
#include <cstddef>

#define NB 512
#define NL 32
#define KD 512    // P*D
#define HKD 256   // k-half per pass

// swizzled float-offset of chunk ch (4 floats) of row `row` in a [32][256] pass buffer.
__device__ __forceinline__ int swz_off(int row, int ch) {
  int csw = (ch & ~15) | ((ch ^ (row >> 1)) & 15);
  return row * HKD + csw * 4;
}

// ---------------- cost kernel: 512 blocks x 256 thr (verified; unchanged) ----------------
__global__ __launch_bounds__(256, 2)
void cost_kernel(const float* __restrict__ pred, const float* __restrict__ tgt,
                 float* __restrict__ cost_g) {
  __shared__ float smem[16384];   // 64 KB staging; later 4x1024 partials
  const int b = blockIdx.x;
  const int tid = threadIdx.x;
  float* predH = smem;
  float* tgtH  = smem + 8192;

  const int w = tid >> 6, l = tid & 63;
  const int ti = l >> 3, tj = l & 7;   // 8x8 lanes of 4x4 tiles, wave w owns a k-slice
  float acc[4][4];
#pragma unroll
  for (int a = 0; a < 4; ++a)
#pragma unroll
    for (int c2 = 0; c2 < 4; ++c2) acc[a][c2] = 0.f;

  for (int hp = 0; hp < 2; ++hp) {
    __syncthreads();
    const size_t base = (size_t)b * (NL * KD) + (size_t)hp * HKD;
#pragma unroll
    for (int it = 0; it < 8; ++it) {
      int chunk = tid + it * 256;
      int row = chunk >> 6, ch = chunk & 63;
      const float4 pv = *reinterpret_cast<const float4*>(pred + base + (size_t)row * KD + ch * 4);
      const float4 tv = *reinterpret_cast<const float4*>(tgt  + base + (size_t)row * KD + ch * 4);
      int off = swz_off(row, ch);
      *reinterpret_cast<float4*>(predH + off) = pv;
      *reinterpret_cast<float4*>(tgtH  + off) = tv;
    }
    __syncthreads();
#pragma unroll
    for (int c0 = 0; c0 < 16; ++c0) {
      const int c = (w << 4) + c0;
      float4 pr[4], tg[4];
#pragma unroll
      for (int r = 0; r < 4; ++r) {
        pr[r] = *reinterpret_cast<const float4*>(predH + swz_off(4 * ti + r, c));
        tg[r] = *reinterpret_cast<const float4*>(tgtH  + swz_off(4 * tj + r, c));
      }
#pragma unroll
      for (int a = 0; a < 4; ++a)
#pragma unroll
        for (int c2 = 0; c2 < 4; ++c2) {
          float d;
          d = pr[a].x - tg[c2].x; acc[a][c2] += d * d;
          d = pr[a].y - tg[c2].y; acc[a][c2] += d * d;
          d = pr[a].z - tg[c2].z; acc[a][c2] += d * d;
          d = pr[a].w - tg[c2].w; acc[a][c2] += d * d;
        }
    }
  }
  __syncthreads();   // staging reads done; reuse LDS for partials
  // disjoint bit-field layout: bank = (ti&3)+4*tj -> 2-way max (free)
#pragma unroll
  for (int a = 0; a < 4; ++a)
#pragma unroll
    for (int c2 = 0; c2 < 4; ++c2)
      smem[w * 1024 + (ti & 3) + 4 * tj + 32 * a + 128 * c2 + 512 * (ti >> 2)] = acc[a][c2];
  __syncthreads();
  const int ti2 = tid >> 5, a2 = (tid >> 3) & 3, tj2 = tid & 7;
  float ov[4];
#pragma unroll
  for (int k = 0; k < 4; ++k) {
    int ad = (ti2 & 3) + 4 * tj2 + 32 * a2 + 128 * k + 512 * (ti2 >> 2);
    ov[k] = (smem[ad] + smem[ad + 1024]) + (smem[ad + 2048] + smem[ad + 3072]);
  }
  float4 o4 = make_float4(ov[0], ov[1], ov[2], ov[3]);
  *reinterpret_cast<float4*>(cost_g + (size_t)b * 1024 + tid * 4) = o4;
}

// ---------------- hungarian kernel: 512 blocks x 64 thr ----------------
__device__ __forceinline__ float readlane_f(float x, int lane) {
  return __int_as_float(__builtin_amdgcn_readlane(__float_as_int(x), lane));
}
__device__ __forceinline__ int readlane_i(int x, int lane) {
  return __builtin_amdgcn_readlane(x, lane);
}

template<int CTRL, int RM>
__device__ __forceinline__ float dppmin(float x) {
  int m = __builtin_amdgcn_update_dpp(__float_as_int(x), __float_as_int(x), CTRL, RM, 0xf, false);
  return fminf(x, __int_as_float(m));
}
// min over lanes 0..31, broadcast to all lanes via SGPR
__device__ __forceinline__ float wave_min32_bcast(float x) {
  x = dppmin<0xB1, 0xf>(x);   // quad_perm xor1
  x = dppmin<0x4E, 0xf>(x);   // quad_perm xor2
  x = dppmin<0x124, 0xf>(x);  // row_ror:4
  x = dppmin<0x128, 0xf>(x);  // row_ror:8 -> row16 min everywhere
  x = dppmin<0x142, 0xa>(x);  // row_bcast:15 -> lanes 16..31 = min(lanes 0..31)
  return readlane_f(x, 31);
}

// named-register 32-way select: NO arrays anywhere (rule #20: arrays with
// dynamic-looking idx get demoted to scratch/LDS -> R4's 110us disaster).
#define SEL32(res, idx)                                                        \
  {                                                                            \
    const int _i = (idx);                                                      \
    float t0 = (_i & 16) ? c16 : c0,  t1 = (_i & 16) ? c17 : c1;               \
    float t2 = (_i & 16) ? c18 : c2,  t3 = (_i & 16) ? c19 : c3;               \
    float t4 = (_i & 16) ? c20 : c4,  t5 = (_i & 16) ? c21 : c5;               \
    float t6 = (_i & 16) ? c22 : c6,  t7 = (_i & 16) ? c23 : c7;               \
    float t8 = (_i & 16) ? c24 : c8,  t9 = (_i & 16) ? c25 : c9;               \
    float t10 = (_i & 16) ? c26 : c10, t11 = (_i & 16) ? c27 : c11;            \
    float t12 = (_i & 16) ? c28 : c12, t13 = (_i & 16) ? c29 : c13;            \
    float t14 = (_i & 16) ? c30 : c14, t15 = (_i & 16) ? c31 : c15;            \
    float u0 = (_i & 8) ? t8 : t0,   u1 = (_i & 8) ? t9 : t1;                  \
    float u2 = (_i & 8) ? t10 : t2,  u3 = (_i & 8) ? t11 : t3;                 \
    float u4 = (_i & 8) ? t12 : t4,  u5 = (_i & 8) ? t13 : t5;                 \
    float u6 = (_i & 8) ? t14 : t6,  u7 = (_i & 8) ? t15 : t7;                 \
    float v0 = (_i & 4) ? u4 : u0,   v1 = (_i & 4) ? u5 : u1;                  \
    float v2 = (_i & 4) ? u6 : u2,   v3 = (_i & 4) ? u7 : u3;                  \
    float w0 = (_i & 2) ? v2 : v0,   w1 = (_i & 2) ? v3 : v1;                  \
    (res) = (_i & 1) ? w1 : w0;                                                \
  }

#define LDC(N) const float c##N = cb[(N) * 32];

__global__ __launch_bounds__(64)
void hung_kernel(const float* __restrict__ cost_g,
                 const float* __restrict__ prob,
                 const float* __restrict__ lmask,
                 const int* __restrict__ clf,
                 float* __restrict__ part) {
  const int b = blockIdx.x;
  const int lane = threadIdx.x;

  float lm = (lane < 32) ? lmask[b * 32 + lane] : 0.f;
  const int n = __popcll(__ballot(lm > 0.5f));
  float clfpart = 0.f;
  if (lane < 32 && lm > 0.5f) {
    int cc = clf[b * 32 + lane];
    clfpart = -logf(prob[(size_t)(b * 32 + lane) * 2 + cc]);
  }

  // lane j owns column j: cost[i][j] for i=0..31 in 32 NAMED registers
  const int cl = (lane < 32) ? lane : 0;
  const float* cb = cost_g + (size_t)b * 1024 + cl;
  LDC(0) LDC(1) LDC(2) LDC(3) LDC(4) LDC(5) LDC(6) LDC(7)
  LDC(8) LDC(9) LDC(10) LDC(11) LDC(12) LDC(13) LDC(14) LDC(15)
  LDC(16) LDC(17) LDC(18) LDC(19) LDC(20) LDC(21) LDC(22) LDC(23)
  LDC(24) LDC(25) LDC(26) LDC(27) LDC(28) LDC(29) LDC(30) LDC(31)

  const float FINF = 1e30f;
  const bool activecol = (lane < n);

  // Reference-faithful broken JV (minv/way never persisted in the python):
  // each step: fresh argmin over free cols of cost[i0][j]-u[i0]-v[j];
  // "augment" collapses to p[j_final] = ri. The uniform u[i0] doesn't affect
  // the argmin, so the min runs on key = c - v; delta = min(key) - u[i0].
  float u_r = 0.f, v_j = 0.f;
  int p_j = -1;

  for (int ri = 0; ri < n; ++ri) {
    int i0 = ri;
    bool usedc = false;
    bool usedr = (lane == ri);
    while (true) {
      float selc;
      SEL32(selc, i0);
      float key = selc - v_j;                   // reduced cost (sans uniform u0)
      bool act = activecol && !usedc;
      float m = act ? key : FINF;
      float u0 = readlane_f(u_r, i0);           // off the min critical path
      float mn = wave_min32_bcast(m);
      uint64_t tie = __ballot(m == mn);
      int j1 = __ffsll((unsigned long long)tie) - 1;  // numpy first-index tie-break
      float delta = mn - u0;
      if (usedr) u_r += delta;                  // u[p[used]] += delta
      if (usedc) v_j -= delta;                  // v[used]    -= delta
      int pj1 = readlane_i(p_j, j1);
      if (pj1 < 0) {                            // free column -> p[j1] = ri, done
        if (lane == j1) p_j = ri;
        break;
      }
      usedc = usedc || (lane == j1);
      i0 = pj1;
      usedr = usedr || (lane == i0);
    }
  }

  // column j matched to row p[j] -> contributes cost[p[j]][j]
  int pj = p_j < 0 ? 0 : p_j;
  float a;
  SEL32(a, pj);
  a = activecol ? a : 0.f;
#pragma unroll
  for (int off = 32; off; off >>= 1) {
    a += __shfl_xor(a, off);
    clfpart += __shfl_xor(clfpart, off);
  }
  if (lane == 0) {
    part[b * 3 + 0] = a;
    part[b * 3 + 1] = clfpart;
    part[b * 3 + 2] = (float)n;
  }
}

// ---------------- finalize ----------------
__global__ void finalize_kernel(const float* __restrict__ part, float* __restrict__ out) {
  const int lane = threadIdx.x;   // 64 threads, 1 block: deterministic fixed-order reduce
  double cs = 0.0, ls = 0.0, ns = 0.0;
  for (int i = lane; i < NB; i += 64) {
    cs += (double)part[i * 3 + 0];
    ls += (double)part[i * 3 + 1];
    ns += (double)part[i * 3 + 2];
  }
#pragma unroll
  for (int off = 32; off; off >>= 1) {
    cs += __shfl_xor(cs, off);
    ls += __shfl_xor(ls, off);
    ns += __shfl_xor(ns, off);
  }
  if (lane == 0) {
    out[0] = (float)(cs / (ns * 256.0));  // / sum(point_masks) = 256 * sum(n)
    out[1] = (float)(ls / ns);            // / sum(line_masks)
  }
}

extern "C" void kernel_launch(void* const* d_in, const int* in_sizes, int n_in,
                              void* d_out, int out_size, void* d_ws, size_t ws_size,
                              hipStream_t stream) {
  const float* pred = (const float*)d_in[0];   // [512,32,256,2] f32
  const float* prob = (const float*)d_in[1];   // [512,32,2] f32
  const float* tgt  = (const float*)d_in[2];   // [512,32,256,2] f32
  const float* lm   = (const float*)d_in[3];   // [512,32] f32
  const int*   clf  = (const int*)d_in[4];     // [512,32] i32

  float* cost_g = (float*)d_ws;                // 512*1024 f32 = 2 MB
  float* part   = cost_g + (size_t)NB * 1024;  // 512*3 f32

  cost_kernel<<<NB, 256, 0, stream>>>(pred, tgt, cost_g);
  hung_kernel<<<NB, 64, 0, stream>>>(cost_g, prob, lm, clf, part);
  finalize_kernel<<<1, 64, 0, stream>>>(part, (float*)d_out);
}

// Round 6
// 85.222 us; speedup vs baseline: 1.8056x; 1.0514x over previous
//
#include <hip/hip_runtime.h>
#include <cstdint>
#include <cstddef>

#define NB 512
#define NL 32
#define KD 512    // P*D
#define HKD 256   // k-half per pass

// swizzled float-offset of chunk ch (4 floats) of row `row` in a [32][256] pass buffer.
__device__ __forceinline__ int swz_off(int row, int ch) {
  int csw = (ch & ~15) | ((ch ^ (row >> 1)) & 15);
  return row * HKD + csw * 4;
}

// ---------------- cost kernel: 512 blocks x 256 thr (verified; unchanged) ----------------
__global__ __launch_bounds__(256, 2)
void cost_kernel(const float* __restrict__ pred, const float* __restrict__ tgt,
                 float* __restrict__ cost_g) {
  __shared__ float smem[16384];   // 64 KB staging; later 4x1024 partials
  const int b = blockIdx.x;
  const int tid = threadIdx.x;
  float* predH = smem;
  float* tgtH  = smem + 8192;

  const int w = tid >> 6, l = tid & 63;
  const int ti = l >> 3, tj = l & 7;   // 8x8 lanes of 4x4 tiles, wave w owns a k-slice
  float acc[4][4];
#pragma unroll
  for (int a = 0; a < 4; ++a)
#pragma unroll
    for (int c2 = 0; c2 < 4; ++c2) acc[a][c2] = 0.f;

  for (int hp = 0; hp < 2; ++hp) {
    __syncthreads();
    const size_t base = (size_t)b * (NL * KD) + (size_t)hp * HKD;
#pragma unroll
    for (int it = 0; it < 8; ++it) {
      int chunk = tid + it * 256;
      int row = chunk >> 6, ch = chunk & 63;
      const float4 pv = *reinterpret_cast<const float4*>(pred + base + (size_t)row * KD + ch * 4);
      const float4 tv = *reinterpret_cast<const float4*>(tgt  + base + (size_t)row * KD + ch * 4);
      int off = swz_off(row, ch);
      *reinterpret_cast<float4*>(predH + off) = pv;
      *reinterpret_cast<float4*>(tgtH  + off) = tv;
    }
    __syncthreads();
#pragma unroll
    for (int c0 = 0; c0 < 16; ++c0) {
      const int c = (w << 4) + c0;
      float4 pr[4], tg[4];
#pragma unroll
      for (int r = 0; r < 4; ++r) {
        pr[r] = *reinterpret_cast<const float4*>(predH + swz_off(4 * ti + r, c));
        tg[r] = *reinterpret_cast<const float4*>(tgtH  + swz_off(4 * tj + r, c));
      }
#pragma unroll
      for (int a = 0; a < 4; ++a)
#pragma unroll
        for (int c2 = 0; c2 < 4; ++c2) {
          float d;
          d = pr[a].x - tg[c2].x; acc[a][c2] += d * d;
          d = pr[a].y - tg[c2].y; acc[a][c2] += d * d;
          d = pr[a].z - tg[c2].z; acc[a][c2] += d * d;
          d = pr[a].w - tg[c2].w; acc[a][c2] += d * d;
        }
    }
  }
  __syncthreads();   // staging reads done; reuse LDS for partials
  // disjoint bit-field layout: bank = (ti&3)+4*tj -> 2-way max (free)
#pragma unroll
  for (int a = 0; a < 4; ++a)
#pragma unroll
    for (int c2 = 0; c2 < 4; ++c2)
      smem[w * 1024 + (ti & 3) + 4 * tj + 32 * a + 128 * c2 + 512 * (ti >> 2)] = acc[a][c2];
  __syncthreads();
  const int ti2 = tid >> 5, a2 = (tid >> 3) & 3, tj2 = tid & 7;
  float ov[4];
#pragma unroll
  for (int k = 0; k < 4; ++k) {
    int ad = (ti2 & 3) + 4 * tj2 + 32 * a2 + 128 * k + 512 * (ti2 >> 2);
    ov[k] = (smem[ad] + smem[ad + 1024]) + (smem[ad + 2048] + smem[ad + 3072]);
  }
  float4 o4 = make_float4(ov[0], ov[1], ov[2], ov[3]);
  *reinterpret_cast<float4*>(cost_g + (size_t)b * 1024 + tid * 4) = o4;
}

// ---------------- hungarian kernel: 512 blocks x 64 thr ----------------
__device__ __forceinline__ float readlane_f(float x, int lane) {
  return __int_as_float(__builtin_amdgcn_readlane(__float_as_int(x), lane));
}
__device__ __forceinline__ int readlane_i(int x, int lane) {
  return __builtin_amdgcn_readlane(x, lane);
}

template<int CTRL, int RM>
__device__ __forceinline__ float dppmin(float x) {
  int m = __builtin_amdgcn_update_dpp(__float_as_int(x), __float_as_int(x), CTRL, RM, 0xf, false);
  return fminf(x, __int_as_float(m));
}
// min over lanes 0..31, broadcast to all lanes via SGPR
__device__ __forceinline__ float wave_min32_bcast(float x) {
  x = dppmin<0xB1, 0xf>(x);   // quad_perm xor1
  x = dppmin<0x4E, 0xf>(x);   // quad_perm xor2
  x = dppmin<0x124, 0xf>(x);  // row_ror:4
  x = dppmin<0x128, 0xf>(x);  // row_ror:8 -> row16 min everywhere
  x = dppmin<0x142, 0xa>(x);  // row_bcast:15 -> lanes 16..31 = min(lanes 0..31)
  return readlane_f(x, 31);
}

// named-register 32-way select (31 v_cndmask). Leaves are OPAQUE registers
// (see KEEP8 below), so LLVM cannot fold this back into an indexed load.
#define SEL32(res, idx)                                                        \
  {                                                                            \
    const int _i = (idx);                                                      \
    float t0 = (_i & 16) ? c16 : c0,  t1 = (_i & 16) ? c17 : c1;               \
    float t2 = (_i & 16) ? c18 : c2,  t3 = (_i & 16) ? c19 : c3;               \
    float t4 = (_i & 16) ? c20 : c4,  t5 = (_i & 16) ? c21 : c5;               \
    float t6 = (_i & 16) ? c22 : c6,  t7 = (_i & 16) ? c23 : c7;               \
    float t8 = (_i & 16) ? c24 : c8,  t9 = (_i & 16) ? c25 : c9;               \
    float t10 = (_i & 16) ? c26 : c10, t11 = (_i & 16) ? c27 : c11;            \
    float t12 = (_i & 16) ? c28 : c12, t13 = (_i & 16) ? c29 : c13;            \
    float t14 = (_i & 16) ? c30 : c14, t15 = (_i & 16) ? c31 : c15;            \
    float u0 = (_i & 8) ? t8 : t0,   u1 = (_i & 8) ? t9 : t1;                  \
    float u2 = (_i & 8) ? t10 : t2,  u3 = (_i & 8) ? t11 : t3;                 \
    float u4 = (_i & 8) ? t12 : t4,  u5 = (_i & 8) ? t13 : t5;                 \
    float u6 = (_i & 8) ? t14 : t6,  u7 = (_i & 8) ? t15 : t7;                 \
    float v0 = (_i & 4) ? u4 : u0,   v1 = (_i & 4) ? u5 : u1;                  \
    float v2 = (_i & 4) ? u6 : u2,   v3 = (_i & 4) ? u7 : u3;                  \
    float w0 = (_i & 2) ? v2 : v0,   w1 = (_i & 2) ? v3 : v1;                  \
    (res) = (_i & 1) ? w1 : w0;                                                \
  }

#define LDC(N) float c##N = cb[(N) * 32];
// Opaque-register barrier: defeats "select of loads -> load of select"
// (R5: compiler folded SEL32 back to a dependent global load per iteration;
//  VGPR_Count=28 proved the column was never register-resident).
#define KEEP8(a,b,c,d,e,f,g,h) \
  asm volatile("" : "+v"(a), "+v"(b), "+v"(c), "+v"(d), "+v"(e), "+v"(f), "+v"(g), "+v"(h));

__global__ __launch_bounds__(64)
void hung_kernel(const float* __restrict__ cost_g,
                 const float* __restrict__ prob,
                 const float* __restrict__ lmask,
                 const int* __restrict__ clf,
                 float* __restrict__ part) {
  const int b = blockIdx.x;
  const int lane = threadIdx.x;

  float lm = (lane < 32) ? lmask[b * 32 + lane] : 0.f;
  const int n = __popcll(__ballot(lm > 0.5f));
  float clfpart = 0.f;
  if (lane < 32 && lm > 0.5f) {
    int cc = clf[b * 32 + lane];
    clfpart = -logf(prob[(size_t)(b * 32 + lane) * 2 + cc]);
  }

  // lane j owns column j: cost[i][j] for i=0..31 in 32 NAMED registers
  const int cl = (lane < 32) ? lane : 0;
  const float* cb = cost_g + (size_t)b * 1024 + cl;
  LDC(0) LDC(1) LDC(2) LDC(3) LDC(4) LDC(5) LDC(6) LDC(7)
  LDC(8) LDC(9) LDC(10) LDC(11) LDC(12) LDC(13) LDC(14) LDC(15)
  LDC(16) LDC(17) LDC(18) LDC(19) LDC(20) LDC(21) LDC(22) LDC(23)
  LDC(24) LDC(25) LDC(26) LDC(27) LDC(28) LDC(29) LDC(30) LDC(31)
  KEEP8(c0, c1, c2, c3, c4, c5, c6, c7)
  KEEP8(c8, c9, c10, c11, c12, c13, c14, c15)
  KEEP8(c16, c17, c18, c19, c20, c21, c22, c23)
  KEEP8(c24, c25, c26, c27, c28, c29, c30, c31)

  const float FINF = 1e30f;
  const bool activecol = (lane < n);

  // Reference-faithful broken JV (minv/way never persisted in the python):
  // each step: fresh argmin over free cols of cost[i0][j]-u[i0]-v[j];
  // "augment" collapses to p[j_final] = ri. The uniform u[i0] doesn't affect
  // the argmin, so the min runs on key = c - v; delta = min(key) - u[i0].
  float u_r = 0.f, v_j = 0.f;
  int p_j = -1;

  for (int ri = 0; ri < n; ++ri) {
    int i0 = ri;
    bool usedc = false;
    bool usedr = (lane == ri);
    while (true) {
      float selc;
      SEL32(selc, i0);
      float key = selc - v_j;                   // reduced cost (sans uniform u0)
      bool act = activecol && !usedc;
      float m = act ? key : FINF;
      float u0 = readlane_f(u_r, i0);           // off the min critical path
      float mn = wave_min32_bcast(m);
      uint64_t tie = __ballot(m == mn);
      int j1 = __ffsll((unsigned long long)tie) - 1;  // numpy first-index tie-break
      float delta = mn - u0;
      if (usedr) u_r += delta;                  // u[p[used]] += delta
      if (usedc) v_j -= delta;                  // v[used]    -= delta
      int pj1 = readlane_i(p_j, j1);
      if (pj1 < 0) {                            // free column -> p[j1] = ri, done
        if (lane == j1) p_j = ri;
        break;
      }
      usedc = usedc || (lane == j1);
      i0 = pj1;
      usedr = usedr || (lane == i0);
    }
  }

  // column j matched to row p[j] -> contributes cost[p[j]][j]
  int pj = p_j < 0 ? 0 : p_j;
  float a;
  SEL32(a, pj);
  a = activecol ? a : 0.f;
#pragma unroll
  for (int off = 32; off; off >>= 1) {
    a += __shfl_xor(a, off);
    clfpart += __shfl_xor(clfpart, off);
  }
  if (lane == 0) {
    part[b * 3 + 0] = a;
    part[b * 3 + 1] = clfpart;
    part[b * 3 + 2] = (float)n;
  }
}

// ---------------- finalize ----------------
__global__ void finalize_kernel(const float* __restrict__ part, float* __restrict__ out) {
  const int lane = threadIdx.x;   // 64 threads, 1 block: deterministic fixed-order reduce
  double cs = 0.0, ls = 0.0, ns = 0.0;
  for (int i = lane; i < NB; i += 64) {
    cs += (double)part[i * 3 + 0];
    ls += (double)part[i * 3 + 1];
    ns += (double)part[i * 3 + 2];
  }
#pragma unroll
  for (int off = 32; off; off >>= 1) {
    cs += __shfl_xor(cs, off);
    ls += __shfl_xor(ls, off);
    ns += __shfl_xor(ns, off);
  }
  if (lane == 0) {
    out[0] = (float)(cs / (ns * 256.0));  // / sum(point_masks) = 256 * sum(n)
    out[1] = (float)(ls / ns);            // / sum(line_masks)
  }
}

extern "C" void kernel_launch(void* const* d_in, const int* in_sizes, int n_in,
                              void* d_out, int out_size, void* d_ws, size_t ws_size,
                              hipStream_t stream) {
  const float* pred = (const float*)d_in[0];   // [512,32,256,2] f32
  const float* prob = (const float*)d_in[1];   // [512,32,2] f32
  const float* tgt  = (const float*)d_in[2];   // [512,32,256,2] f32
  const float* lm   = (const float*)d_in[3];   // [512,32] f32
  const int*   clf  = (const int*)d_in[4];     // [512,32] i32

  float* cost_g = (float*)d_ws;                // 512*1024 f32 = 2 MB
  float* part   = cost_g + (size_t)NB * 1024;  // 512*3 f32

  cost_kernel<<<NB, 256, 0, stream>>>(pred, tgt, cost_g);
  hung_kernel<<<NB, 64, 0, stream>>>(cost_g, prob, lm, clf, part);
  finalize_kernel<<<1, 64, 0, stream>>>(part, (float*)d_out);
}

// Round 7
// 73.069 us; speedup vs baseline: 2.1060x; 1.1663x over previous
//
#include <hip/hip_runtime.h>
#include <cstdint>
#include <cstddef>

#define NB 512
#define NL 32
#define KD 512    // P*D
#define HKD 256   // k-half per pass

// swizzled float-offset of chunk ch (4 floats) of row `row` in a [32][256] pass buffer.
__device__ __forceinline__ int swz_off(int row, int ch) {
  int csw = (ch & ~15) | ((ch ^ (row >> 1)) & 15);
  return row * HKD + csw * 4;
}

// ---------------- cost kernel: 512 blocks x 256 thr (verified; unchanged) ----------------
__global__ __launch_bounds__(256, 2)
void cost_kernel(const float* __restrict__ pred, const float* __restrict__ tgt,
                 float* __restrict__ cost_g) {
  __shared__ float smem[16384];   // 64 KB staging; later 4x1024 partials
  const int b = blockIdx.x;
  const int tid = threadIdx.x;
  float* predH = smem;
  float* tgtH  = smem + 8192;

  const int w = tid >> 6, l = tid & 63;
  const int ti = l >> 3, tj = l & 7;   // 8x8 lanes of 4x4 tiles, wave w owns a k-slice
  float acc[4][4];
#pragma unroll
  for (int a = 0; a < 4; ++a)
#pragma unroll
    for (int c2 = 0; c2 < 4; ++c2) acc[a][c2] = 0.f;

  for (int hp = 0; hp < 2; ++hp) {
    __syncthreads();
    const size_t base = (size_t)b * (NL * KD) + (size_t)hp * HKD;
#pragma unroll
    for (int it = 0; it < 8; ++it) {
      int chunk = tid + it * 256;
      int row = chunk >> 6, ch = chunk & 63;
      const float4 pv = *reinterpret_cast<const float4*>(pred + base + (size_t)row * KD + ch * 4);
      const float4 tv = *reinterpret_cast<const float4*>(tgt  + base + (size_t)row * KD + ch * 4);
      int off = swz_off(row, ch);
      *reinterpret_cast<float4*>(predH + off) = pv;
      *reinterpret_cast<float4*>(tgtH  + off) = tv;
    }
    __syncthreads();
#pragma unroll
    for (int c0 = 0; c0 < 16; ++c0) {
      const int c = (w << 4) + c0;
      float4 pr[4], tg[4];
#pragma unroll
      for (int r = 0; r < 4; ++r) {
        pr[r] = *reinterpret_cast<const float4*>(predH + swz_off(4 * ti + r, c));
        tg[r] = *reinterpret_cast<const float4*>(tgtH  + swz_off(4 * tj + r, c));
      }
#pragma unroll
      for (int a = 0; a < 4; ++a)
#pragma unroll
        for (int c2 = 0; c2 < 4; ++c2) {
          float d;
          d = pr[a].x - tg[c2].x; acc[a][c2] += d * d;
          d = pr[a].y - tg[c2].y; acc[a][c2] += d * d;
          d = pr[a].z - tg[c2].z; acc[a][c2] += d * d;
          d = pr[a].w - tg[c2].w; acc[a][c2] += d * d;
        }
    }
  }
  __syncthreads();   // staging reads done; reuse LDS for partials
  // disjoint bit-field layout: bank = (ti&3)+4*tj -> 2-way max (free)
#pragma unroll
  for (int a = 0; a < 4; ++a)
#pragma unroll
    for (int c2 = 0; c2 < 4; ++c2)
      smem[w * 1024 + (ti & 3) + 4 * tj + 32 * a + 128 * c2 + 512 * (ti >> 2)] = acc[a][c2];
  __syncthreads();
  const int ti2 = tid >> 5, a2 = (tid >> 3) & 3, tj2 = tid & 7;
  float ov[4];
#pragma unroll
  for (int k = 0; k < 4; ++k) {
    int ad = (ti2 & 3) + 4 * tj2 + 32 * a2 + 128 * k + 512 * (ti2 >> 2);
    ov[k] = (smem[ad] + smem[ad + 1024]) + (smem[ad + 2048] + smem[ad + 3072]);
  }
  float4 o4 = make_float4(ov[0], ov[1], ov[2], ov[3]);
  *reinterpret_cast<float4*>(cost_g + (size_t)b * 1024 + tid * 4) = o4;
}

// ---------------- hungarian kernel: 512 blocks x 64 thr ----------------
__device__ __forceinline__ float readlane_f(float x, int lane) {
  return __int_as_float(__builtin_amdgcn_readlane(__float_as_int(x), lane));
}
__device__ __forceinline__ int readlane_i(int x, int lane) {
  return __builtin_amdgcn_readlane(x, lane);
}

template<int CTRL, int RM>
__device__ __forceinline__ float dppmin(float x) {
  int m = __builtin_amdgcn_update_dpp(__float_as_int(x), __float_as_int(x), CTRL, RM, 0xf, false);
  return fminf(x, __int_as_float(m));
}
// min over lanes 0..31, broadcast to all lanes via SGPR
__device__ __forceinline__ float wave_min32_bcast(float x) {
  x = dppmin<0xB1, 0xf>(x);   // quad_perm xor1
  x = dppmin<0x4E, 0xf>(x);   // quad_perm xor2
  x = dppmin<0x124, 0xf>(x);  // row_ror:4
  x = dppmin<0x128, 0xf>(x);  // row_ror:8 -> row16 min everywhere
  x = dppmin<0x142, 0xa>(x);  // row_bcast:15 -> lanes 16..31 = min(lanes 0..31)
  return readlane_f(x, 31);
}

__global__ __launch_bounds__(64)
void hung_kernel(const float* __restrict__ cost_g,
                 const float* __restrict__ prob,
                 const float* __restrict__ lmask,
                 const int* __restrict__ clf,
                 float* __restrict__ part) {
  __shared__ float cs[1024];    // cost[32][32]: row-select = 1 conflict-free ds_read_b32
  const int b = blockIdx.x;
  const int lane = threadIdx.x;

  // stage cost into LDS (4 float4 per lane), overlapping the mask/prob loads
  {
    const float4* src = reinterpret_cast<const float4*>(cost_g + (size_t)b * 1024);
    float4* dst = reinterpret_cast<float4*>(cs);
#pragma unroll
    for (int k = 0; k < 4; ++k) dst[lane + 64 * k] = src[lane + 64 * k];
  }

  float lm = (lane < 32) ? lmask[b * 32 + lane] : 0.f;
  const int n = __popcll(__ballot(lm > 0.5f));
  float clfpart = 0.f;
  if (lane < 32 && lm > 0.5f) {
    int cc = clf[b * 32 + lane];
    clfpart = -logf(prob[(size_t)(b * 32 + lane) * 2 + cc]);
  }
  __syncthreads();   // LDS cost visible (single wave: waitcnt)

  const float FINF = 1e30f;
  const bool activecol = (lane < n);
  const int cl = lane & 31;     // lanes 32..63 mirror 0..31 -> same-addr broadcast (free)

  // Reference-faithful broken JV (minv/way never persisted in the python):
  // each step: fresh argmin over free cols of cost[i0][j]-u[i0]-v[j];
  // "augment" collapses to p[j_final] = ri. The uniform u[i0] doesn't affect
  // the argmin, so the min runs on key = c - v; delta = min(key) - u[i0].
  float u_r = 0.f, v_j = 0.f;
  int p_j = -1;

  for (int ri = 0; ri < n; ++ri) {
    int i0 = ri;
    bool usedc = false;
    bool usedr = (lane == ri);
    float rowv = cs[i0 * 32 + cl];
    while (true) {
      float key = rowv - v_j;                   // reduced cost (sans uniform u0)
      bool act = activecol && !usedc;
      float m = act ? key : FINF;
      float u0 = readlane_f(u_r, i0);           // off the min critical path
      float mn = wave_min32_bcast(m);
      uint64_t tie = __ballot(m == mn);
      int j1 = __ffsll((unsigned long long)tie) - 1;  // numpy first-index tie-break
      int pj1 = readlane_i(p_j, j1);
      int i0n = pj1 < 0 ? 0 : pj1;
      float rowv_n = cs[i0n * 32 + cl];         // speculative next-row read (pre-branch)
      float delta = mn - u0;
      if (usedr) u_r += delta;                  // u[p[used]] += delta
      if (usedc) v_j -= delta;                  // v[used]    -= delta
      if (pj1 < 0) {                            // free column -> p[j1] = ri, done
        if (lane == j1) p_j = ri;
        break;
      }
      usedc = usedc || (lane == j1);
      i0 = pj1;
      usedr = usedr || (lane == i0);
      rowv = rowv_n;
    }
  }

  // column j matched to row p[j] -> contributes cost[p[j]][j]
  int pj = p_j < 0 ? 0 : p_j;
  float a = activecol ? cs[pj * 32 + cl] : 0.f;
#pragma unroll
  for (int off = 32; off; off >>= 1) {
    a += __shfl_xor(a, off);
    clfpart += __shfl_xor(clfpart, off);
  }
  if (lane == 0) {
    part[b * 3 + 0] = a;
    part[b * 3 + 1] = clfpart;
    part[b * 3 + 2] = (float)n;
  }
}

// ---------------- finalize ----------------
__global__ void finalize_kernel(const float* __restrict__ part, float* __restrict__ out) {
  const int lane = threadIdx.x;   // 64 threads, 1 block: deterministic fixed-order reduce
  double cs = 0.0, ls = 0.0, ns = 0.0;
  for (int i = lane; i < NB; i += 64) {
    cs += (double)part[i * 3 + 0];
    ls += (double)part[i * 3 + 1];
    ns += (double)part[i * 3 + 2];
  }
#pragma unroll
  for (int off = 32; off; off >>= 1) {
    cs += __shfl_xor(cs, off);
    ls += __shfl_xor(ls, off);
    ns += __shfl_xor(ns, off);
  }
  if (lane == 0) {
    out[0] = (float)(cs / (ns * 256.0));  // / sum(point_masks) = 256 * sum(n)
    out[1] = (float)(ls / ns);            // / sum(line_masks)
  }
}

extern "C" void kernel_launch(void* const* d_in, const int* in_sizes, int n_in,
                              void* d_out, int out_size, void* d_ws, size_t ws_size,
                              hipStream_t stream) {
  const float* pred = (const float*)d_in[0];   // [512,32,256,2] f32
  const float* prob = (const float*)d_in[1];   // [512,32,2] f32
  const float* tgt  = (const float*)d_in[2];   // [512,32,256,2] f32
  const float* lm   = (const float*)d_in[3];   // [512,32] f32
  const int*   clf  = (const int*)d_in[4];     // [512,32] i32

  float* cost_g = (float*)d_ws;                // 512*1024 f32 = 2 MB
  float* part   = cost_g + (size_t)NB * 1024;  // 512*3 f32

  cost_kernel<<<NB, 256, 0, stream>>>(pred, tgt, cost_g);
  hung_kernel<<<NB, 64, 0, stream>>>(cost_g, prob, lm, clf, part);
  finalize_kernel<<<1, 64, 0, stream>>>(part, (float*)d_out);
}